// Round 11
// baseline (101.866 us; speedup 1.0000x reference)
//
#include <hip/hip_runtime.h>

// ---------------------------------------------------------------------------
// PANet disparity head — TWO-kernel pipeline for MI355X (gfx950).
//
// K1 panet_encode: encoder (x,y -> bf16 xf,yf) + writes per-row 2-parity
//   hankel copies to global + wd transposed to PA[kw][row][16B] + bd*log2e.
// K2 panet_corr: LDS-FREE, BARRIER-FREE correlation + online softmax.
//   R11 theory: K2 was DS-pipe-bound (~36us/CU of ds instrs; occupancy pinned
//   ~1.5 WG/CU across 5 configs). Feed MFMA operands straight from global:
//   * B fragment = contiguous window hank[s..s+7]; 2 parity copies in global
//     make every fragment a 4B-aligned dwordx4; lane windows overlap 14/16B
//     -> ~100B per wave-load, row L1-resident.
//   * A pre-transposed (PA[kw][row][16B]) -> per-load 2x512B contiguous;
//     identical across the block's waves -> L1 serves 3/4+ of traffic.
//   MFMA issue floor is only 3.8us/CU (4608 mfma32 x 8cyc / 4 SIMD) — the
//   rest was memory-pipe: move it to VMEM and let TLP overlap it.
// ws usage ~3.9 MB (plain 1MB + hankel 2.9MB + PA 74KB + bd).
// ---------------------------------------------------------------------------

typedef __attribute__((ext_vector_type(8)))  __bf16 bf16x8;
typedef __attribute__((ext_vector_type(8), aligned(4))) __bf16 bf16x8u; // 4B-aligned frag
typedef __attribute__((ext_vector_type(4)))  float  f32x4;
typedef __attribute__((ext_vector_type(16))) float  f32x16;

#define MFMA32(a,b,c) __builtin_amdgcn_mfma_f32_32x32x16_bf16((a),(b),(c),0,0,0)
#define MFMA16(a,b,c) __builtin_amdgcn_mfma_f32_16x16x32_bf16((a),(b),(c),0,0,0)

constexpr int WW  = 512;
constexpr int HW  = 256 * 512;      // 131072
constexpr int CHW = 32 * HW;        // 4194304
constexpr float LOG2E = 1.4426950408889634f;

// d_ws layout:
constexpr size_t XFB_OFF = 0;                        // ushort [2 img][512][512] = 1MB
constexpr size_t HKG_OFF = 1048576;                  // ushort [2 dir][512 row][2 p][712]
constexpr int    HRP     = 2848;                     // hankel row pitch (bytes)
constexpr size_t HDP     = 512ull * HRP;             // dir pitch 1458176
constexpr size_t PA_OFF  = HKG_OFF + 2 * HDP;        // 3964928: [24 kw][192 row][16B]
constexpr size_t BDP_OFF = PA_OFF + 73728;           // f32[192] = bd * LOG2E

// ---------------------------------------------------------------- K1
__global__ __launch_bounds__(512)
void panet_encode(const float* __restrict__ gx,  const float* __restrict__ gy,
                  const float* __restrict__ gw1, const float* __restrict__ gb1,
                  const float* __restrict__ gw2, const float* __restrict__ gb2,
                  const float* __restrict__ gw3, const float* __restrict__ gb3,
                  const float* __restrict__ gwd, const float* __restrict__ gbd,
                  char* __restrict__ ws)
{
  const int blk = blockIdx.x;
  const int tid = threadIdx.x;

  if (blk >= 1024) {                          // ---- packer blocks 1024..1039
    const int pi = blk - 1024;                // 16 blocks
    // (a) wd -> PA[kw][row][16B], rows [12pi, 12pi+12)
    char* pab = ws + PA_OFF;
    for (int idx = tid; idx < 12 * 192; idx += 512) {  // 12 rows x 24 kw x 8 j
      const int rr = idx / 192;
      const int rem = idx - rr * 192;
      const int kw = rem >> 3;
      const int j  = rem & 7;
      const int row = 12 * pi + rr;
      const __bf16 v = (__bf16)gwd[row * 192 + 8 * kw + j];
      ((unsigned short*)(pab + (kw * 192 + row) * 16))[j] =
          __builtin_bit_cast(unsigned short, v);
    }
    // (b) hankel tails zero: rows [32pi, 32pi+32), both dirs/copies
    unsigned short* hkb = (unsigned short*)(ws + HKG_OFF);
    for (int d = 0; d < 2; ++d)
      for (int rr = 0; rr < 32; ++rr) {
        unsigned short* hk = hkb + d * (HDP / 2) + (size_t)(32 * pi + rr) * (HRP / 2);
        for (int e = 512 + tid; e < 712; e += 512) hk[e] = 0;        // copy0 tail
        for (int e = 511 + tid; e < 712; e += 512) hk[712 + e] = 0;  // copy1 tail
      }
    // (c) bd * log2e
    if (pi == 0) {
      float* bdp = (float*)(ws + BDP_OFF);
      if (tid < 192) bdp[tid] = gbd[tid] * LOG2E;
    }
    return;
  }

  // ---- encoder: blk -> (t = image, bh). Proven R3..R10 body.
  const int t    = blk >> 9;
  const int bh   = blk & 511;
  const int lane = tid & 63;
  const int m    = lane & 15;
  const int g    = lane >> 4;
  const int wid  = tid >> 6;

  bf16x8 A1[4], A2[2][2];
  f32x4  bias1[4], bias2[2], w3v[2];
  #pragma unroll
  for (int Mt = 0; Mt < 4; ++Mt) {
    const float* p = gw1 + (16 * Mt + m) * 32 + 4 * g;
    const f32x4 u0 = *(const f32x4*)p;
    const f32x4 u1 = *(const f32x4*)(p + 16);
    #pragma unroll
    for (int j = 0; j < 4; ++j) { A1[Mt][j] = (__bf16)u0[j]; A1[Mt][j + 4] = (__bf16)u1[j]; }
    bias1[Mt] = *(const f32x4*)(gb1 + 16 * Mt + 4 * g);
  }
  #pragma unroll
  for (int Mt = 0; Mt < 2; ++Mt) {
    #pragma unroll
    for (int s = 0; s < 2; ++s) {
      const float* p = gw2 + (16 * Mt + m) * 64 + 32 * s + 4 * g;
      const f32x4 u0 = *(const f32x4*)p;
      const f32x4 u1 = *(const f32x4*)(p + 16);
      #pragma unroll
      for (int j = 0; j < 4; ++j) { A2[Mt][s][j] = (__bf16)u0[j]; A2[Mt][s][j + 4] = (__bf16)u1[j]; }
    }
    bias2[Mt] = *(const f32x4*)(gb2 + 16 * Mt + 4 * g);
    w3v[Mt]   = *(const f32x4*)(gw3 + 16 * Mt + 4 * g);
  }
  const float b3s = gb3[0];
  const f32x4 zf4 = {0.f, 0.f, 0.f, 0.f};
  const float* base = (t ? gy : gx) + (bh >> 8) * CHW + (bh & 255) * WW;
  unsigned short* xfb = (unsigned short*)(ws + XFB_OFF) + t * 262144 + bh * 512;
  unsigned short* hk  = (unsigned short*)(ws + HKG_OFF) + t * (HDP / 2) + (size_t)bh * (HRP / 2);

  for (int u = wid; u < 32; u += 8) {
    const int w0 = u << 4;
    const float* src = base + w0 + m;

    bf16x8 B1;
    #pragma unroll
    for (int j = 0; j < 8; ++j) {
      const int c = 16 * (j >> 2) + 4 * g + (j & 3);
      B1[j] = (__bf16)fmaxf(src[c * HW], 0.f);
    }
    f32x4 acc1[4];
    #pragma unroll
    for (int Mt = 0; Mt < 4; ++Mt) acc1[Mt] = MFMA16(A1[Mt], B1, zf4);

    bf16x8 B2[2];
    #pragma unroll
    for (int s = 0; s < 2; ++s) {
      #pragma unroll
      for (int j = 0; j < 4; ++j) {
        B2[s][j]     = (__bf16)fmaxf(acc1[2 * s][j]     + bias1[2 * s][j],     0.f);
        B2[s][j + 4] = (__bf16)fmaxf(acc1[2 * s + 1][j] + bias1[2 * s + 1][j], 0.f);
      }
    }
    f32x4 acc2[2];
    #pragma unroll
    for (int Mt = 0; Mt < 2; ++Mt)
      acc2[Mt] = MFMA16(A2[Mt][1], B2[1], MFMA16(A2[Mt][0], B2[0], zf4));

    float s3 = 0.f;
    #pragma unroll
    for (int Mt = 0; Mt < 2; ++Mt)
      #pragma unroll
      for (int r = 0; r < 4; ++r)
        s3 += w3v[Mt][r] * fmaxf(acc2[Mt][r] + bias2[Mt][r], 0.f);
    s3 += __shfl_xor(s3, 16);
    s3 += __shfl_xor(s3, 32);
    const float val = fmaxf(s3 + b3s, 0.f);

    if (lane < 16) {
      const int px = w0 + m;
      const unsigned short bits = __builtin_bit_cast(unsigned short, (__bf16)val);
      xfb[px] = bits;                               // plain (scale reads)
      if (t == 0) {                                 // dir0 hankel: hank[j]=xf[j]
        hk[px] = bits;                              // copy0[px]
        if (px >= 1) hk[712 + px - 1] = bits;       // copy1[px-1]
      } else {                                      // dir1: hank[j]=yf[511-j]
        hk[511 - px] = bits;                        // copy0[511-px]
        if (px <= 510) hk[712 + 510 - px] = bits;   // copy1[510-px]
      }
    }
  }
}

// ---------------------------------------------------------------- K2
// LDS-free, barrier-free. Per wave: 64 cols (2 ct), 2x2 mfma32 blocking,
// 3 row-stages of 64, online softmax in exp2 domain.
__global__ __launch_bounds__(256)
void panet_corr(const char* __restrict__ ws, float* __restrict__ gout)
{
  const int blk  = blockIdx.x;                // dir*1024 + bh*2 + colhalf
  const int dir  = blk >> 10;
  const int bh   = (blk >> 1) & 511;
  const int ch2  = blk & 1;
  const int tid  = threadIdx.x;
  const int lane = tid & 63;
  const int l31  = lane & 31;
  const int h    = lane >> 5;                 // lane half
  const int wid  = tid >> 6;                  // 4 waves

  const unsigned short* xfbu = (const unsigned short*)(ws + XFB_OFF);
  const unsigned short* ss = xfbu + (dir ? 0 : 262144) + bh * 512;   // scale row
  const char* hkrow = ws + HKG_OFF + dir * HDP + (size_t)bh * HRP;
  const char* pa    = ws + PA_OFF;
  const float* bdp  = (const float*)(ws + BDP_OFF);

  // per-lane B window bases + scales
  const char* bptr[2]; float sc[2];
  #pragma unroll
  for (int ct = 0; ct < 2; ++ct) {
    const int col = ch2 * 256 + wid * 64 + ct * 32 + l31;
    const int I0  = dir ? (511 - col) : col;
    const int p   = I0 & 1;
    // fragment start s = I0 + 16ks + 8h; byte = p*1424 + 2*(I0-p) + 16h + 32ks
    bptr[ct] = hkrow + p * 1424 + 2 * (I0 - p) + 16 * h;
    sc[ct]  = LOG2E * __builtin_bit_cast(float, (unsigned)ss[col] << 16);
  }

  float stM[2] = {-3.4e38f, -3.4e38f};
  float stS[2] = {0.f, 0.f};
  float stW[2] = {0.f, 0.f};

  for (int s = 0; s < 3; ++s) {               // 3 x 64 wd rows
    f32x16 a00 = {0}, a01 = {0}, a10 = {0}, a11 = {0};
    // A addr: PA + ((2ks+h)*192 + 64s + l31)*16 = abase + ks*6144 (+512 for +32 rows)
    const char* abase = pa + (h * 192 + 64 * s + l31) * 16;
    #pragma unroll 2
    for (int ks = 0; ks < 12; ++ks) {         // K = 12*16 = 192
      const bf16x8 af0 = __builtin_bit_cast(bf16x8, *(const bf16x8u*)(abase + ks * 6144));
      const bf16x8 af1 = __builtin_bit_cast(bf16x8, *(const bf16x8u*)(abase + ks * 6144 + 512));
      const bf16x8 bf0 = __builtin_bit_cast(bf16x8, *(const bf16x8u*)(bptr[0] + 32 * ks));
      const bf16x8 bf1 = __builtin_bit_cast(bf16x8, *(const bf16x8u*)(bptr[1] + 32 * ks));
      a00 = MFMA32(af0, bf0, a00);
      a01 = MFMA32(af0, bf1, a01);
      a10 = MFMA32(af1, bf0, a10);
      a11 = MFMA32(af1, bf1, a11);
    }

    // online softmax (exp2 domain), ILP-restructured, raw v_exp_f32
    #pragma unroll
    for (int ct = 0; ct < 2; ++ct) {
      const f32x16 A0 = ct ? a01 : a00;       // rt=0 rows
      const f32x16 A1 = ct ? a11 : a10;       // rt=1 rows (+32)
      float L0[16], L1[16];
      #pragma unroll
      for (int q = 0; q < 4; ++q) {
        const f32x4 bd0 = *(const f32x4*)(bdp + 64 * s + 8 * q + 4 * h);
        const f32x4 bd1 = *(const f32x4*)(bdp + 64 * s + 8 * q + 4 * h + 32);
        #pragma unroll
        for (int r = 0; r < 4; ++r) {
          L0[4 * q + r] = fmaf(sc[ct], A0[4 * q + r], bd0[r]);
          L1[4 * q + r] = fmaf(sc[ct], A1[4 * q + r], bd1[r]);
        }
      }
      // depth-5 parallel max tree
      float t[16];
      #pragma unroll
      for (int i = 0; i < 16; ++i) t[i] = fmaxf(L0[i], L1[i]);
      #pragma unroll
      for (int off = 8; off > 0; off >>= 1)
        #pragma unroll
        for (int i = 0; i < off; ++i) t[i] = fmaxf(t[i], t[i + off]);
      const float nm   = fmaxf(stM[ct], t[0]);
      const float fold = __builtin_amdgcn_exp2f(stM[ct] - nm);
      // 4-way partial chains; o-constants folded at compile time
      float lsp[4] = {0.f, 0.f, 0.f, 0.f}, lwp[4] = {0.f, 0.f, 0.f, 0.f};
      #pragma unroll
      for (int i = 0; i < 16; ++i) {
        const float c  = (float)((i & 3) + 8 * (i >> 2));   // row_rel - 4h
        const float p0 = __builtin_amdgcn_exp2f(L0[i] - nm);
        const float p1 = __builtin_amdgcn_exp2f(L1[i] - nm);
        lsp[i & 3] += p0 + p1;
        lwp[i & 3] = fmaf(c, p0, lwp[i & 3]);
        lwp[i & 3] = fmaf(c + 32.f, p1, lwp[i & 3]);
      }
      float ls = (lsp[0] + lsp[1]) + (lsp[2] + lsp[3]);
      float lw = (lwp[0] + lwp[1]) + (lwp[2] + lwp[3]);
      lw = fmaf((float)(64 * s + 4 * h), ls, lw);
      stS[ct] = fmaf(stS[ct], fold, ls);
      stW[ct] = fmaf(stW[ct], fold, lw);
      stM[ct] = nm;
    }
  }

  // final: combine the two lane-halves (rows split by h), then write
  float* outp = gout + dir * 262144 + bh * 512 + ch2 * 256;
  #pragma unroll
  for (int ct = 0; ct < 2; ++ct) {
    const float Mo = __shfl_xor(stM[ct], 32);
    const float M  = fmaxf(stM[ct], Mo);
    const float f  = __builtin_amdgcn_exp2f(stM[ct] - M);
    float sr = stS[ct] * f;
    float wr = stW[ct] * f;
    sr += __shfl_xor(sr, 32);
    wr += __shfl_xor(wr, 32);
    if (lane < 32) outp[wid * 64 + ct * 32 + l31] = wr / sr;
  }
}

extern "C" void kernel_launch(void* const* d_in, const int* in_sizes, int n_in,
                              void* d_out, int out_size, void* d_ws, size_t ws_size,
                              hipStream_t stream) {
  const float* x  = (const float*)d_in[0];
  const float* y  = (const float*)d_in[1];
  const float* w1 = (const float*)d_in[2];
  const float* b1 = (const float*)d_in[3];
  const float* w2 = (const float*)d_in[4];
  const float* b2 = (const float*)d_in[5];
  const float* w3 = (const float*)d_in[6];
  const float* b3 = (const float*)d_in[7];
  const float* wd = (const float*)d_in[8];
  const float* bd = (const float*)d_in[9];
  char* ws = (char*)d_ws;

  panet_encode<<<1040, 512, 0, stream>>>(x, y, w1, b1, w2, b2, w3, b3, wd, bd, ws);
  panet_corr<<<2048, 256, 0, stream>>>(ws, (float*)d_out);
}

// Round 12
// 98.320 us; speedup vs baseline: 1.0361x; 1.0361x over previous
//
#include <hip/hip_runtime.h>

// ---------------------------------------------------------------------------
// PANet disparity head — TWO-kernel pipeline for MI355X (gfx950).
//
// K1 panet_encode: encoder (x,y -> bf16 xf,yf) + 2-parity hankel copies in
//   global + wd packed as 400B-stride LDS image + bd*log2e.
// K2 panet_corr (R12): HYBRID operand sourcing, barrier-free main loop.
//   * A (wd) from LDS: full 192x400B image staged ONCE per block (77.6KB x
//     2 blocks/CU = 155KB fits). DS = shared 128B/cyc path.
//   * B (hankel windows) from GLOBAL: ~100B/wave-load, L1-resident
//     (R11-verified addressing; R11 also showed A-from-global is the slow part).
//   * NO-max softmax: L = sc*acc+bd bounded ~+-60 (N(0,1/fan) weights, relu
//     O(1) activations) -> exp2 safe in f32; sc=0 -> p=exp2(bd), no NaN.
//     Cuts max-tree/sub/fold VALU (~33%) and the serial max dependency.
//   * One barrier per block; each wave owns independent (dir,row,half) work.
// R11 falsified: occupancy ~20% even with ZERO LDS -> pin is the unified
// VGPR+AGPR file (120+64 ~ 184/wave -> 2 waves/SIMD). Stop chasing TLP; cut
// per-CU pipe work: DS 27->16us, VALU 26->~13us, MFMA floor 15.5us stays.
// ---------------------------------------------------------------------------

typedef __attribute__((ext_vector_type(8)))  __bf16 bf16x8;
typedef __attribute__((ext_vector_type(8), aligned(4))) __bf16 bf16x8u;
typedef __attribute__((ext_vector_type(4)))  float  f32x4;
typedef __attribute__((ext_vector_type(16))) float  f32x16;

#define MFMA32(a,b,c) __builtin_amdgcn_mfma_f32_32x32x16_bf16((a),(b),(c),0,0,0)
#define MFMA16(a,b,c) __builtin_amdgcn_mfma_f32_16x16x32_bf16((a),(b),(c),0,0,0)

constexpr int WW  = 512;
constexpr int HW  = 256 * 512;      // 131072
constexpr int CHW = 32 * HW;        // 4194304
constexpr float LOG2E = 1.4426950408889634f;

// d_ws layout:
constexpr size_t XFB_OFF = 0;                        // ushort [2 img][512][512] = 1MB
constexpr size_t HKG_OFF = 1048576;                  // ushort [2 dir][512 row][2 p][712]
constexpr int    HRP     = 2848;                     // hankel row pitch (bytes)
constexpr size_t HDP     = 512ull * HRP;             // dir pitch 1458176
constexpr size_t WDP_OFF = HKG_OFF + 2 * HDP;        // 3964928: wd image 3x64x400B
constexpr size_t BDP_OFF = WDP_OFF + 76800;          // f32[192] = bd * LOG2E

// ---------------------------------------------------------------- K1
__global__ __launch_bounds__(512)
void panet_encode(const float* __restrict__ gx,  const float* __restrict__ gy,
                  const float* __restrict__ gw1, const float* __restrict__ gb1,
                  const float* __restrict__ gw2, const float* __restrict__ gb2,
                  const float* __restrict__ gw3, const float* __restrict__ gb3,
                  const float* __restrict__ gwd, const float* __restrict__ gbd,
                  char* __restrict__ ws)
{
  const int blk = blockIdx.x;
  const int tid = threadIdx.x;

  if (blk >= 1024) {                          // ---- packer blocks 1024..1039
    const int pi = blk - 1024;                // 16 blocks, 12 o-rows each
    unsigned short* wdp = (unsigned short*)(ws + WDP_OFF);
    for (int idx = tid; idx < 12 * 200; idx += 512) {  // 200 ushort per 400B row
      const int oo = idx / 200;
      const int k  = idx - oo * 200;
      const int o  = 12 * pi + oo;
      unsigned short v = 0;
      if (k < 192) v = __builtin_bit_cast(unsigned short, (__bf16)gwd[o * 192 + k]);
      wdp[(o >> 6) * 12800 + (o & 63) * 200 + k] = v;
    }
    // hankel tails zero: rows [32pi, 32pi+32), both dirs/copies
    unsigned short* hkb = (unsigned short*)(ws + HKG_OFF);
    for (int d = 0; d < 2; ++d)
      for (int rr = 0; rr < 32; ++rr) {
        unsigned short* hk = hkb + d * (HDP / 2) + (size_t)(32 * pi + rr) * (HRP / 2);
        for (int e = 512 + tid; e < 712; e += 512) hk[e] = 0;        // copy0 tail
        for (int e = 511 + tid; e < 712; e += 512) hk[712 + e] = 0;  // copy1 tail
      }
    if (pi == 0) {
      float* bdp = (float*)(ws + BDP_OFF);
      if (tid < 192) bdp[tid] = gbd[tid] * LOG2E;
    }
    return;
  }

  // ---- encoder: blk -> (t = image, bh). Proven R3..R11 body.
  const int t    = blk >> 9;
  const int bh   = blk & 511;
  const int lane = tid & 63;
  const int m    = lane & 15;
  const int g    = lane >> 4;
  const int wid  = tid >> 6;

  bf16x8 A1[4], A2[2][2];
  f32x4  bias1[4], bias2[2], w3v[2];
  #pragma unroll
  for (int Mt = 0; Mt < 4; ++Mt) {
    const float* p = gw1 + (16 * Mt + m) * 32 + 4 * g;
    const f32x4 u0 = *(const f32x4*)p;
    const f32x4 u1 = *(const f32x4*)(p + 16);
    #pragma unroll
    for (int j = 0; j < 4; ++j) { A1[Mt][j] = (__bf16)u0[j]; A1[Mt][j + 4] = (__bf16)u1[j]; }
    bias1[Mt] = *(const f32x4*)(gb1 + 16 * Mt + 4 * g);
  }
  #pragma unroll
  for (int Mt = 0; Mt < 2; ++Mt) {
    #pragma unroll
    for (int s = 0; s < 2; ++s) {
      const float* p = gw2 + (16 * Mt + m) * 64 + 32 * s + 4 * g;
      const f32x4 u0 = *(const f32x4*)p;
      const f32x4 u1 = *(const f32x4*)(p + 16);
      #pragma unroll
      for (int j = 0; j < 4; ++j) { A2[Mt][s][j] = (__bf16)u0[j]; A2[Mt][s][j + 4] = (__bf16)u1[j]; }
    }
    bias2[Mt] = *(const f32x4*)(gb2 + 16 * Mt + 4 * g);
    w3v[Mt]   = *(const f32x4*)(gw3 + 16 * Mt + 4 * g);
  }
  const float b3s = gb3[0];
  const f32x4 zf4 = {0.f, 0.f, 0.f, 0.f};
  const float* base = (t ? gy : gx) + (bh >> 8) * CHW + (bh & 255) * WW;
  unsigned short* xfb = (unsigned short*)(ws + XFB_OFF) + t * 262144 + bh * 512;
  unsigned short* hk  = (unsigned short*)(ws + HKG_OFF) + t * (HDP / 2) + (size_t)bh * (HRP / 2);

  for (int u = wid; u < 32; u += 8) {
    const int w0 = u << 4;
    const float* src = base + w0 + m;

    bf16x8 B1;
    #pragma unroll
    for (int j = 0; j < 8; ++j) {
      const int c = 16 * (j >> 2) + 4 * g + (j & 3);
      B1[j] = (__bf16)fmaxf(src[c * HW], 0.f);
    }
    f32x4 acc1[4];
    #pragma unroll
    for (int Mt = 0; Mt < 4; ++Mt) acc1[Mt] = MFMA16(A1[Mt], B1, zf4);

    bf16x8 B2[2];
    #pragma unroll
    for (int s = 0; s < 2; ++s) {
      #pragma unroll
      for (int j = 0; j < 4; ++j) {
        B2[s][j]     = (__bf16)fmaxf(acc1[2 * s][j]     + bias1[2 * s][j],     0.f);
        B2[s][j + 4] = (__bf16)fmaxf(acc1[2 * s + 1][j] + bias1[2 * s + 1][j], 0.f);
      }
    }
    f32x4 acc2[2];
    #pragma unroll
    for (int Mt = 0; Mt < 2; ++Mt)
      acc2[Mt] = MFMA16(A2[Mt][1], B2[1], MFMA16(A2[Mt][0], B2[0], zf4));

    float s3 = 0.f;
    #pragma unroll
    for (int Mt = 0; Mt < 2; ++Mt)
      #pragma unroll
      for (int r = 0; r < 4; ++r)
        s3 += w3v[Mt][r] * fmaxf(acc2[Mt][r] + bias2[Mt][r], 0.f);
    s3 += __shfl_xor(s3, 16);
    s3 += __shfl_xor(s3, 32);
    const float val = fmaxf(s3 + b3s, 0.f);

    if (lane < 16) {
      const int px = w0 + m;
      const unsigned short bits = __builtin_bit_cast(unsigned short, (__bf16)val);
      xfb[px] = bits;                               // plain (scale reads)
      if (t == 0) {                                 // dir0 hankel: hank[j]=xf[j]
        hk[px] = bits;                              // copy0[px]
        if (px >= 1) hk[712 + px - 1] = bits;       // copy1[px-1]
      } else {                                      // dir1: hank[j]=yf[511-j]
        hk[511 - px] = bits;                        // copy0[511-px]
        if (px <= 510) hk[712 + 510 - px] = bits;   // copy1[510-px]
      }
    }
  }
}

// ---------------------------------------------------------------- K2
// A from LDS (full wd image, staged once), B from global. One barrier total.
// grid 512 x 256thr; wave (blk*4+wid) owns half-unit = (dir,row, 256 cols).
constexpr int K2_BD  = 76800;                 // bd f32[192] after wd image
constexpr int K2_LDS = 77568;

__global__ __launch_bounds__(256)
void panet_corr(const char* __restrict__ ws, float* __restrict__ gout)
{
  __shared__ __align__(16) char lds[K2_LDS];
  const int tid  = threadIdx.x;

  {                                            // stage wd image + bd (once)
    const f32x4* src = (const f32x4*)(ws + WDP_OFF);
    f32x4* dst = (f32x4*)lds;
    #pragma unroll 4
    for (int i = tid; i < 4800; i += 256) dst[i] = src[i];
    const float* bdp = (const float*)(ws + BDP_OFF);
    if (tid < 192) ((float*)(lds + K2_BD))[tid] = bdp[tid];
  }
  __syncthreads();                             // the ONLY barrier

  const int lane = tid & 63;
  const int l31  = lane & 31;
  const int h    = lane >> 5;                  // lane half
  const int wid  = tid >> 6;
  const int gw   = blockIdx.x * 4 + wid;       // 2048 half-units
  const int uhalf= gw & 1;
  const int unit = gw >> 1;                    // (dir, bh)
  const int dir  = unit >> 9;
  const int bh   = unit & 511;

  const unsigned short* xfbu = (const unsigned short*)(ws + XFB_OFF);
  const unsigned short* ss = xfbu + (dir ? 0 : 262144) + bh * 512;   // scale row
  const char* hkrow = ws + HKG_OFF + dir * HDP + (size_t)bh * HRP;
  float* outp = gout + dir * 262144 + bh * 512 + uhalf * 256;

  for (int chunk = 0; chunk < 4; ++chunk) {    // 4 x 64 cols per wave
    const char* bptr[2]; float sc[2];
    #pragma unroll
    for (int ct = 0; ct < 2; ++ct) {
      const int col = uhalf * 256 + chunk * 64 + ct * 32 + l31;
      const int I0  = dir ? (511 - col) : col;
      const int p   = I0 & 1;
      bptr[ct] = hkrow + p * 1424 + 2 * (I0 - p) + 16 * h;
      sc[ct]  = LOG2E * __builtin_bit_cast(float, (unsigned)ss[col] << 16);
    }

    float stS0 = 0.f, stS1 = 0.f, stW0 = 0.f, stW1 = 0.f;

    for (int s = 0; s < 3; ++s) {              // 3 x 64 wd rows
      const char* abase = lds + (64 * s + l31) * 400 + 16 * h;
      f32x16 a00 = {0}, a01 = {0}, a10 = {0}, a11 = {0};
      #pragma unroll 3
      for (int ks = 0; ks < 12; ++ks) {        // K = 12*16 = 192
        const bf16x8 af0 = *(const bf16x8*)(abase + 32 * ks);
        const bf16x8 af1 = *(const bf16x8*)(abase + 12800 + 32 * ks);
        const bf16x8 bf0 = __builtin_bit_cast(bf16x8, *(const bf16x8u*)(bptr[0] + 32 * ks));
        const bf16x8 bf1 = __builtin_bit_cast(bf16x8, *(const bf16x8u*)(bptr[1] + 32 * ks));
        a00 = MFMA32(af0, bf0, a00);
        a01 = MFMA32(af0, bf1, a01);
        a10 = MFMA32(af1, bf0, a10);
        a11 = MFMA32(af1, bf1, a11);
      }

      // NO-max softmax accumulation (exp2 domain; logits bounded)
      const float obase = (float)(64 * s + 4 * h);
      #pragma unroll
      for (int ct = 0; ct < 2; ++ct) {
        float ls0 = 0.f, ls1 = 0.f, lw0 = 0.f, lw1 = 0.f;
        #pragma unroll
        for (int q = 0; q < 4; ++q) {
          const f32x4 bd0 = *(const f32x4*)(lds + K2_BD + (64 * s + 8 * q + 4 * h) * 4);
          const f32x4 bd1 = *(const f32x4*)(lds + K2_BD + (64 * s + 8 * q + 4 * h + 32) * 4);
          #pragma unroll
          for (int r = 0; r < 4; ++r) {
            const int i = 4 * q + r;
            const float L0 = fmaf(sc[ct], (ct ? a01 : a00)[i], bd0[r]);
            const float L1 = fmaf(sc[ct], (ct ? a11 : a10)[i], bd1[r]);
            const float p0 = __builtin_amdgcn_exp2f(L0);
            const float p1 = __builtin_amdgcn_exp2f(L1);
            const float c  = (float)(r + 8 * q);          // o - obase (rt=0)
            ls0 += p0;  ls1 += p1;
            lw0 = fmaf(c, p0, lw0);
            lw1 = fmaf(c + 32.f, p1, lw1);
          }
        }
        const float ls = ls0 + ls1;
        const float lw = fmaf(obase, ls, lw0 + lw1);
        if (ct == 0) { stS0 += ls; stW0 += lw; }
        else         { stS1 += ls; stW1 += lw; }
      }
    }

    // combine the two lane-halves (o split by h) and write
    #pragma unroll
    for (int ct = 0; ct < 2; ++ct) {
      float sr = ct ? stS1 : stS0;
      float wr = ct ? stW1 : stW0;
      sr += __shfl_xor(sr, 32);
      wr += __shfl_xor(wr, 32);
      if (lane < 32) outp[chunk * 64 + ct * 32 + l31] = wr / sr;
    }
  }
}

extern "C" void kernel_launch(void* const* d_in, const int* in_sizes, int n_in,
                              void* d_out, int out_size, void* d_ws, size_t ws_size,
                              hipStream_t stream) {
  const float* x  = (const float*)d_in[0];
  const float* y  = (const float*)d_in[1];
  const float* w1 = (const float*)d_in[2];
  const float* b1 = (const float*)d_in[3];
  const float* w2 = (const float*)d_in[4];
  const float* b2 = (const float*)d_in[5];
  const float* w3 = (const float*)d_in[6];
  const float* b3 = (const float*)d_in[7];
  const float* wd = (const float*)d_in[8];
  const float* bd = (const float*)d_in[9];
  char* ws = (char*)d_ws;

  panet_encode<<<1040, 512, 0, stream>>>(x, y, w1, b1, w2, b2, w3, b3, wd, bd, ws);
  panet_corr<<<512, 256, 0, stream>>>(ws, (float*)d_out);
}

// Round 13
// 81.206 us; speedup vs baseline: 1.2544x; 1.2107x over previous
//
#include <hip/hip_runtime.h>

// ---------------------------------------------------------------------------
// PANet disparity head — TWO-kernel pipeline for MI355X (gfx950).
//
// K1 panet_encode (R9-proven): encoder (x,y -> bf16 xf,yf in ws) + wd packed
//   as 400B-stride LDS image + bd*log2e.
// K2 panet_corr (R13): minimum-DS, ONE-barrier design at the pinned ~8
//   waves/CU occupancy:
//   * full wd (76.8KB) + 8-copy hankel (11.4KB) + bd resident in ONE 89KB
//     dynamic-LDS block; staged once (75 wave-instr); grid 1024 = (dir,row).
//   * exactly one __syncthreads; afterwards 8 waves free-run -> DS/VALU/MFMA
//     cross-wave overlap without barrier lockstep (R9's loss).
//   * bd hoisted per-s, shared across col-tiles; no-max softmax (R12-valid).
//   * A stride-400 conflict-free (R8), B 8-copy 16B-aligned (R10). Both LDS:
//     R11/R12 falsified VMEM operands (latency-bound at 4-8 waves/CU).
// Per-CU pipes: DS ~15us (was 25-36), VALU ~9/SIMD, MFMA 16.3 (fixed floor).
// ---------------------------------------------------------------------------

typedef __attribute__((ext_vector_type(8)))  __bf16 bf16x8;
typedef __attribute__((ext_vector_type(4)))  float  f32x4;
typedef __attribute__((ext_vector_type(16))) float  f32x16;

#define MFMA32(a,b,c) __builtin_amdgcn_mfma_f32_32x32x16_bf16((a),(b),(c),0,0,0)
#define MFMA16(a,b,c) __builtin_amdgcn_mfma_f32_16x16x32_bf16((a),(b),(c),0,0,0)

constexpr int WW  = 512;
constexpr int HW  = 256 * 512;      // 131072
constexpr int CHW = 32 * HW;        // 4194304
constexpr float LOG2E = 1.4426950408889634f;

// d_ws layout (R9):
constexpr size_t XFB_OFF = 0;                   // bf16 [2 img][512 row][512 w]
constexpr int    STB     = 25600;               // 64 rows x 400 B
constexpr size_t WDP_OFF = 2 * 262144 * 2;      // 1048576: wd image 3*25600
constexpr size_t BDP_OFF = WDP_OFF + 3 * STB;   // f32[192] = bd * LOG2E

// ---------------------------------------------------------------- K1
__global__ __launch_bounds__(512)
void panet_encode(const float* __restrict__ gx,  const float* __restrict__ gy,
                  const float* __restrict__ gw1, const float* __restrict__ gb1,
                  const float* __restrict__ gw2, const float* __restrict__ gb2,
                  const float* __restrict__ gw3, const float* __restrict__ gb3,
                  const float* __restrict__ gwd, const float* __restrict__ gbd,
                  char* __restrict__ ws)
{
  const int blk = blockIdx.x;
  const int tid = threadIdx.x;

  if (blk >= 1024) {                          // ---- packer blocks 1024..1039
    const int pi = blk - 1024;                // 16 blocks, 12 o-rows each
    unsigned short* wdp = (unsigned short*)(ws + WDP_OFF);
    for (int idx = tid; idx < 12 * 200; idx += 512) {  // 200 ushort per 400B row
      const int oo = idx / 200;
      const int k  = idx - oo * 200;
      const int o  = 12 * pi + oo;
      unsigned short v = 0;
      if (k < 192) v = __builtin_bit_cast(unsigned short, (__bf16)gwd[o * 192 + k]);
      wdp[(o >> 6) * 12800 + (o & 63) * 200 + k] = v;
    }
    if (pi == 0) {
      float* bdp = (float*)(ws + BDP_OFF);
      if (tid < 192) bdp[tid] = gbd[tid] * LOG2E;
    }
    return;
  }

  // ---- encoder: blk -> (t = image, bh). Proven R3..R12 body.
  const int t    = blk >> 9;
  const int bh   = blk & 511;
  const int lane = tid & 63;
  const int m    = lane & 15;
  const int g    = lane >> 4;
  const int wid  = tid >> 6;

  bf16x8 A1[4], A2[2][2];
  f32x4  bias1[4], bias2[2], w3v[2];
  #pragma unroll
  for (int Mt = 0; Mt < 4; ++Mt) {
    const float* p = gw1 + (16 * Mt + m) * 32 + 4 * g;
    const f32x4 u0 = *(const f32x4*)p;
    const f32x4 u1 = *(const f32x4*)(p + 16);
    #pragma unroll
    for (int j = 0; j < 4; ++j) { A1[Mt][j] = (__bf16)u0[j]; A1[Mt][j + 4] = (__bf16)u1[j]; }
    bias1[Mt] = *(const f32x4*)(gb1 + 16 * Mt + 4 * g);
  }
  #pragma unroll
  for (int Mt = 0; Mt < 2; ++Mt) {
    #pragma unroll
    for (int s = 0; s < 2; ++s) {
      const float* p = gw2 + (16 * Mt + m) * 64 + 32 * s + 4 * g;
      const f32x4 u0 = *(const f32x4*)p;
      const f32x4 u1 = *(const f32x4*)(p + 16);
      #pragma unroll
      for (int j = 0; j < 4; ++j) { A2[Mt][s][j] = (__bf16)u0[j]; A2[Mt][s][j + 4] = (__bf16)u1[j]; }
    }
    bias2[Mt] = *(const f32x4*)(gb2 + 16 * Mt + 4 * g);
    w3v[Mt]   = *(const f32x4*)(gw3 + 16 * Mt + 4 * g);
  }
  const float b3s = gb3[0];
  const f32x4 zf4 = {0.f, 0.f, 0.f, 0.f};
  const float* base = (t ? gy : gx) + (bh >> 8) * CHW + (bh & 255) * WW;
  unsigned short* xfb = (unsigned short*)(ws + XFB_OFF) + t * 262144 + bh * 512;

  for (int u = wid; u < 32; u += 8) {
    const int w0 = u << 4;
    const float* src = base + w0 + m;

    bf16x8 B1;
    #pragma unroll
    for (int j = 0; j < 8; ++j) {
      const int c = 16 * (j >> 2) + 4 * g + (j & 3);
      B1[j] = (__bf16)fmaxf(src[c * HW], 0.f);
    }
    f32x4 acc1[4];
    #pragma unroll
    for (int Mt = 0; Mt < 4; ++Mt) acc1[Mt] = MFMA16(A1[Mt], B1, zf4);

    bf16x8 B2[2];
    #pragma unroll
    for (int s = 0; s < 2; ++s) {
      #pragma unroll
      for (int j = 0; j < 4; ++j) {
        B2[s][j]     = (__bf16)fmaxf(acc1[2 * s][j]     + bias1[2 * s][j],     0.f);
        B2[s][j + 4] = (__bf16)fmaxf(acc1[2 * s + 1][j] + bias1[2 * s + 1][j], 0.f);
      }
    }
    f32x4 acc2[2];
    #pragma unroll
    for (int Mt = 0; Mt < 2; ++Mt)
      acc2[Mt] = MFMA16(A2[Mt][1], B2[1], MFMA16(A2[Mt][0], B2[0], zf4));

    float s3 = 0.f;
    #pragma unroll
    for (int Mt = 0; Mt < 2; ++Mt)
      #pragma unroll
      for (int r = 0; r < 4; ++r)
        s3 += w3v[Mt][r] * fmaxf(acc2[Mt][r] + bias2[Mt][r], 0.f);
    s3 += __shfl_xor(s3, 16);
    s3 += __shfl_xor(s3, 32);
    const float val = fmaxf(s3 + b3s, 0.f);

    if (lane < 16)
      xfb[w0 + m] = __builtin_bit_cast(unsigned short, (__bf16)val);
  }
}

// ---------------------------------------------------------------- K2
constexpr int CPS    = 1424;                  // hankel copy stride (bytes)
constexpr int K2_HK  = 76800;                 // after full wd image
constexpr int K2_BD  = K2_HK + 8 * CPS;       // 88192: f32[192]
constexpr int K2_LDS = K2_BD + 768;           // 88960 B dynamic

__global__ __launch_bounds__(512)
void panet_corr(const char* __restrict__ ws, float* __restrict__ gout)
{
  extern __shared__ __align__(16) char lds[];
  const int blk  = blockIdx.x;                // dir*512 + bh
  const int dir  = blk >> 9;
  const int bh   = blk & 511;
  const int tid  = threadIdx.x;
  const int lane = tid & 63;
  const int l31  = lane & 31;
  const int h    = lane >> 5;                 // lane half
  const int wid  = tid >> 6;                  // 8 waves, 64 cols each

  const unsigned short* xfbu = (const unsigned short*)(ws + XFB_OFF);
  const unsigned short* hs = xfbu + (dir ? 262144 : 0) + bh * 512;  // hankel src
  const unsigned short* ss = xfbu + (dir ? 0 : 262144) + bh * 512;  // scale src

  // ---- stage wd image + bd; build 8-copy hankel (zeros beyond 511)
  {
    const f32x4* src = (const f32x4*)(ws + WDP_OFF);
    f32x4* dst = (f32x4*)lds;
    #pragma unroll 5
    for (int i = tid; i < 4800; i += 512) dst[i] = src[i];
    if (tid < 192)
      ((float*)(lds + K2_BD))[tid] = ((const float*)(ws + BDP_OFF))[tid];
  }
  for (int e = tid; e < 712; e += 512) {
    #pragma unroll
    for (int c = 0; c < 8; ++c) {
      const int j = e + c;
      unsigned short v = 0;
      if (j <= 511) v = hs[dir ? (511 - j) : j];
      ((unsigned short*)(lds + K2_HK + c * CPS))[e] = v;
    }
  }
  __syncthreads();                             // the ONLY barrier

  // per-lane B bases + scales (2 col-tiles of 32; 64 cols per wave)
  const char* bptr[2]; float sc[2];
  #pragma unroll
  for (int ct = 0; ct < 2; ++ct) {
    const int col = wid * 64 + ct * 32 + l31;
    const int I0  = dir ? (511 - col) : col;
    const int cc  = I0 & 7;
    bptr[ct] = lds + K2_HK + cc * CPS + 2 * (I0 - cc) + 16 * h;
    sc[ct]  = LOG2E * __builtin_bit_cast(float, (unsigned)ss[col] << 16);
  }

  float stS0 = 0.f, stS1 = 0.f, stW0 = 0.f, stW1 = 0.f;

  for (int s = 0; s < 3; ++s) {               // 3 x 64 wd rows
    const char* abase = lds + (64 * s + l31) * 400 + 16 * h;
    f32x16 a00 = {0}, a01 = {0}, a10 = {0}, a11 = {0};
    #pragma unroll 4
    for (int ks = 0; ks < 12; ++ks) {         // K = 12*16 = 192
      const bf16x8 af0 = *(const bf16x8*)(abase + 32 * ks);
      const bf16x8 af1 = *(const bf16x8*)(abase + 12800 + 32 * ks);
      const bf16x8 bf0 = *(const bf16x8*)(bptr[0] + 32 * ks);
      const bf16x8 bf1 = *(const bf16x8*)(bptr[1] + 32 * ks);
      a00 = MFMA32(af0, bf0, a00);
      a01 = MFMA32(af0, bf1, a01);
      a10 = MFMA32(af1, bf0, a10);
      a11 = MFMA32(af1, bf1, a11);
    }

    // bd for this s, shared across both col-tiles
    f32x4 bdr0[4], bdr1[4];
    #pragma unroll
    for (int q = 0; q < 4; ++q) {
      bdr0[q] = *(const f32x4*)(lds + K2_BD + (64 * s + 8 * q + 4 * h) * 4);
      bdr1[q] = *(const f32x4*)(lds + K2_BD + (64 * s + 8 * q + 4 * h + 32) * 4);
    }
    const float obase = (float)(64 * s + 4 * h);

    // NO-max softmax accumulation (exp2 domain; logits bounded)
    #pragma unroll
    for (int ct = 0; ct < 2; ++ct) {
      float ls0 = 0.f, ls1 = 0.f, lw0 = 0.f, lw1 = 0.f;
      #pragma unroll
      for (int q = 0; q < 4; ++q) {
        #pragma unroll
        for (int r = 0; r < 4; ++r) {
          const int i = 4 * q + r;
          const float L0 = fmaf(sc[ct], (ct ? a01 : a00)[i], bdr0[q][r]);
          const float L1 = fmaf(sc[ct], (ct ? a11 : a10)[i], bdr1[q][r]);
          const float p0 = __builtin_amdgcn_exp2f(L0);
          const float p1 = __builtin_amdgcn_exp2f(L1);
          const float c  = (float)(r + 8 * q);          // o - obase (rt=0)
          ls0 += p0;  ls1 += p1;
          lw0 = fmaf(c, p0, lw0);
          lw1 = fmaf(c + 32.f, p1, lw1);
        }
      }
      const float ls = ls0 + ls1;
      const float lw = fmaf(obase, ls, lw0 + lw1);
      if (ct == 0) { stS0 += ls; stW0 += lw; }
      else         { stS1 += ls; stW1 += lw; }
    }
  }

  // combine the two lane-halves (o split by h) and write
  float* outp = gout + dir * 262144 + bh * 512;
  #pragma unroll
  for (int ct = 0; ct < 2; ++ct) {
    float sr = ct ? stS1 : stS0;
    float wr = ct ? stW1 : stW0;
    sr += __shfl_xor(sr, 32);
    wr += __shfl_xor(wr, 32);
    if (lane < 32) outp[wid * 64 + ct * 32 + l31] = wr / sr;
  }
}

extern "C" void kernel_launch(void* const* d_in, const int* in_sizes, int n_in,
                              void* d_out, int out_size, void* d_ws, size_t ws_size,
                              hipStream_t stream) {
  const float* x  = (const float*)d_in[0];
  const float* y  = (const float*)d_in[1];
  const float* w1 = (const float*)d_in[2];
  const float* b1 = (const float*)d_in[3];
  const float* w2 = (const float*)d_in[4];
  const float* b2 = (const float*)d_in[5];
  const float* w3 = (const float*)d_in[6];
  const float* b3 = (const float*)d_in[7];
  const float* wd = (const float*)d_in[8];
  const float* bd = (const float*)d_in[9];
  char* ws = (char*)d_ws;

  (void)hipFuncSetAttribute((const void*)panet_corr,
                            hipFuncAttributeMaxDynamicSharedMemorySize, K2_LDS);
  panet_encode<<<1040, 512, 0, stream>>>(x, y, w1, b1, w2, b2, w3, b3, wd, bd, ws);
  panet_corr<<<1024, 512, K2_LDS, stream>>>(ws, (float*)d_out);
}